// Round 12
// baseline (1328.017 us; speedup 1.0000x reference)
//
#include <hip/hip_runtime.h>
#include <hip/hip_bf16.h>
#include <math.h>

#define N_ROWS 65536
#define ZDIM   256
#define KCODES 1024
#define IDX_OFF  (N_ROWS * ZDIM)        // 16777216
#define LOSS_OFF (IDX_OFF + N_ROWS)     // 16842752
#define ZQ_BLOCKS 2048
#define SLOTS 2
#define NC16 16                          // 16 chunks of 64 codes

typedef unsigned int u32;
typedef unsigned short u16;
typedef __attribute__((ext_vector_type(8))) short bfrag;   // 8 bf16 (4 VGPR)
typedef __attribute__((ext_vector_type(4))) float ffrag;   // 4 fp32 acc

__device__ __forceinline__ u16 f2bf(float x) {
    __hip_bfloat16 h = __float2bfloat16(x);      // RN
    union { __hip_bfloat16 h; u16 u; } c; c.h = h; return c.u;
}

// ---------------- numpy-pairwise helpers (256 cols) ----------------
__device__ __forceinline__ float np_pw128_sq(const float* __restrict__ p) {
    float r[8];
#pragma unroll
    for (int j = 0; j < 8; ++j) r[j] = __fmul_rn(p[j], p[j]);
    for (int i = 8; i < 128; i += 8) {
#pragma unroll
        for (int j = 0; j < 8; ++j)
            r[j] = __fadd_rn(r[j], __fmul_rn(p[i + j], p[i + j]));
    }
    float a = __fadd_rn(__fadd_rn(r[0], r[1]), __fadd_rn(r[2], r[3]));
    float b = __fadd_rn(__fadd_rn(r[4], r[5]), __fadd_rn(r[6], r[7]));
    return __fadd_rn(a, b);
}

__device__ __forceinline__ float pw128_abs(const float* __restrict__ p) {
    float r[8];
#pragma unroll
    for (int j = 0; j < 8; ++j) r[j] = fabsf(p[j]);
    for (int i = 8; i < 128; i += 8) {
#pragma unroll
        for (int j = 0; j < 8; ++j) r[j] += fabsf(p[i + j]);
    }
    return ((r[0] + r[1]) + (r[2] + r[3])) + ((r[4] + r[5]) + (r[6] + r[7]));
}

__global__ void rowsq_kernel(const float* __restrict__ x, float* __restrict__ s, int nrows) {
    int r = blockIdx.x * blockDim.x + threadIdx.x;
    if (r >= nrows) return;
    const float* p = x + (size_t)r * ZDIM;
    s[r] = __fadd_rn(np_pw128_sq(p), np_pw128_sq(p + 128));
}

// sz (np-exact) + per-row rigorous eps for the 1-pass bf16 bound
__global__ void rowsq_eps_kernel(const float* __restrict__ x, float* __restrict__ s,
                                 float* __restrict__ epsr) {
    int r = blockIdx.x * blockDim.x + threadIdx.x;
    const float* p = x + (size_t)r * ZDIM;
    s[r] = __fadd_rn(np_pw128_sq(p), np_pw128_sq(p + 128));
    float S1 = pw128_abs(p) + pw128_abs(p + 128);
    epsr[r] = fmaf(S1, 8.4e-6f, 1.2e-4f);
}

// ---------------- z -> bf16 (RN), row-major, into d_out z_q region ----------
__global__ __launch_bounds__(256) void split_z_kernel(
    const float* __restrict__ z, u16* __restrict__ zh) {
    int t = blockIdx.x * 256 + threadIdx.x;
    int i = t * 8;
    float4 a = *(const float4*)(z + i);
    float4 b = *(const float4*)(z + i + 4);
    uint4 w;
    w.x = ((u32)f2bf(a.y) << 16) | f2bf(a.x);
    w.y = ((u32)f2bf(a.w) << 16) | f2bf(a.z);
    w.z = ((u32)f2bf(b.y) << 16) | f2bf(b.x);
    w.w = ((u32)f2bf(b.w) << 16) | f2bf(b.z);
    *(uint4*)(zh + i) = w;
}

// ---------------- e -> bf16, FRAGMENT-MAJOR layout ----------------
// B-fragment for (c16, kc, ct) is 1024B contiguous: 64 lanes x 8 shorts.
// lane = lk*16 + lr holds code c16*64+ct*16+lr, dims kc*32+lk*8 .. +7.
// addr_short = (((c16*8 + kc)*4 + ct)*64 + lane)*8 + (k & 7)
__global__ __launch_bounds__(256) void split_e_kernel(
    const float* __restrict__ e, u16* __restrict__ ehf) {
    int t = blockIdx.x * 256 + threadIdx.x;      // 65536 threads
    int c = t >> 6, kq = t & 63;                 // dims kq*4 .. +3
    float4 v = *(const float4*)(e + (size_t)c * ZDIM + kq * 4);
    ushort4 h;
    h.x = f2bf(v.x); h.y = f2bf(v.y); h.z = f2bf(v.z); h.w = f2bf(v.w);
    int c16 = c >> 6, ct = (c >> 4) & 3, lr = c & 15;
    int kc = kq >> 3, lk = (kq >> 1) & 3;        // (k>>3)&3 with k=kq*4
    int lane = lk * 16 + lr;
    size_t base = ((size_t)((c16 * 8 + kc) * 4 + ct) * 64 + lane) * 8 + ((kq * 4) & 7);
    *(ushort4*)(ehf + base) = h;
}

// ---------------- wave-autonomous 1-pass MFMA + candidate emission ----------
// Grid 1024 = 512 row-panels x 2 code-halves. Block 256 = 4 waves; wave w owns
// rows wr0 = rp*128 + w*32, streams B-fragments DIRECTLY from the L2-resident
// fragment-major image into registers (1 coalesced b128 load per fragment,
// 1-deep static-index prefetch). NO LDS staging, NO DMA, NO inline asm, NO
// main-loop barriers -> no race class. A-frags (64 VGPR) preloaded once.
// Frag maps (r9/r10-verified): A row=lane&15, k=(lane>>4)*8+j; B col=lane&15;
// D col=lane&15, row=(lane>>4)*4+reg.
__global__ __launch_bounds__(256) void mfma_argmin_kernel(
    const u16* __restrict__ zh, const u16* __restrict__ ehf,
    const float* __restrict__ sz, const float* __restrict__ se,
    const float* __restrict__ epsr, float* __restrict__ cqmin,
    int* __restrict__ cnt, int* __restrict__ cand) {
    __shared__ float sse[KCODES];                     // 4 KB
    const int tid = threadIdx.x;
    const int w = tid >> 6, lane = tid & 63;
    const int lr = lane & 15, lk = lane >> 4;
    const int rp = blockIdx.x >> 1, cp = blockIdx.x & 1;
    const int wr0 = rp * 128 + w * 32;

    *(float4*)(sse + tid * 4) = *(const float4*)(se + tid * 4);
    __syncthreads();                                  // only barrier (sse init)

    float szv[2][4], epsv[2][4];
#pragma unroll
    for (int rt = 0; rt < 2; ++rt)
#pragma unroll
        for (int j = 0; j < 4; ++j) {
            szv[rt][j]  = sz[wr0 + rt * 16 + lk * 4 + j];
            epsv[rt][j] = epsr[wr0 + rt * 16 + lk * 4 + j];
        }

    bfrag A[2][8];
#pragma unroll
    for (int rt = 0; rt < 2; ++rt)
#pragma unroll
        for (int kc = 0; kc < 8; ++kc)
            A[rt][kc] = *(const bfrag*)(zh + (size_t)(wr0 + rt * 16 + lr) * ZDIM + kc * 32 + lk * 8);

#pragma unroll 1
    for (int cc = 0; cc < 8; ++cc) {
        const int c16 = cp * 8 + cc;
        ffrag acc[2][4];
#pragma unroll
        for (int rt = 0; rt < 2; ++rt)
#pragma unroll
            for (int ct = 0; ct < 4; ++ct) acc[rt][ct] = (ffrag)(0.0f);

        // B fragments: double reg-buffer, static indices (rule #20)
        bfrag B0[4], B1[4];
        {
            const u16* bb = ehf + (size_t)((c16 * 8 + 0) * 4) * 512 + lane * 8;
#pragma unroll
            for (int ct = 0; ct < 4; ++ct) B0[ct] = *(const bfrag*)(bb + ct * 512);
        }
#pragma unroll
        for (int kc = 0; kc < 8; ++kc) {
            if (kc < 7) {
                const u16* bb = ehf + (size_t)((c16 * 8 + kc + 1) * 4) * 512 + lane * 8;
                if (kc & 1) {
#pragma unroll
                    for (int ct = 0; ct < 4; ++ct) B0[ct] = *(const bfrag*)(bb + ct * 512);
                } else {
#pragma unroll
                    for (int ct = 0; ct < 4; ++ct) B1[ct] = *(const bfrag*)(bb + ct * 512);
                }
            }
            if (kc & 1) {
#pragma unroll
                for (int ct = 0; ct < 4; ++ct) {
                    acc[0][ct] = __builtin_amdgcn_mfma_f32_16x16x32_bf16(A[0][kc], B1[ct], acc[0][ct], 0, 0, 0);
                    acc[1][ct] = __builtin_amdgcn_mfma_f32_16x16x32_bf16(A[1][kc], B1[ct], acc[1][ct], 0, 0, 0);
                }
            } else {
#pragma unroll
                for (int ct = 0; ct < 4; ++ct) {
                    acc[0][ct] = __builtin_amdgcn_mfma_f32_16x16x32_bf16(A[0][kc], B0[ct], acc[0][ct], 0, 0, 0);
                    acc[1][ct] = __builtin_amdgcn_mfma_f32_16x16x32_bf16(A[1][kc], B0[ct], acc[1][ct], 0, 0, 0);
                }
            }
        }

        // ---- epilogue for c16: d~ = fl(fl(sz+se) - 2*m~) ----
        float rmin[2][4];
#pragma unroll
        for (int rt = 0; rt < 2; ++rt)
#pragma unroll
            for (int j = 0; j < 4; ++j) rmin[rt][j] = __builtin_inff();
#pragma unroll
        for (int rt = 0; rt < 2; ++rt)
#pragma unroll
            for (int ct = 0; ct < 4; ++ct) {
                float sec = sse[c16 * 64 + ct * 16 + lr];
#pragma unroll
                for (int j = 0; j < 4; ++j) {
                    float dd = __fsub_rn(__fadd_rn(szv[rt][j], sec), 2.0f * acc[rt][ct][j]);
                    rmin[rt][j] = fminf(rmin[rt][j], dd);
                }
            }
#pragma unroll
        for (int m = 1; m < 16; m <<= 1)
#pragma unroll
            for (int rt = 0; rt < 2; ++rt)
#pragma unroll
                for (int j = 0; j < 4; ++j)
                    rmin[rt][j] = fminf(rmin[rt][j], __shfl_xor(rmin[rt][j], m, 64));
        if (lr == 0) {
#pragma unroll
            for (int rt = 0; rt < 2; ++rt)
#pragma unroll
                for (int j = 0; j < 4; ++j)
                    cqmin[(size_t)(wr0 + rt * 16 + lk * 4 + j) * NC16 + c16] = rmin[rt][j];
        }
#pragma unroll
        for (int rt = 0; rt < 2; ++rt)
#pragma unroll
            for (int j = 0; j < 4; ++j) {
                const float thr = fmaf(2.0f, epsv[rt][j], rmin[rt][j]);
                const int grow = wr0 + rt * 16 + lk * 4 + j;
#pragma unroll
                for (int ct = 0; ct < 4; ++ct) {
                    float dd = __fsub_rn(__fadd_rn(szv[rt][j], sse[c16 * 64 + ct * 16 + lr]),
                                         2.0f * acc[rt][ct][j]);
                    if (dd <= thr) {
                        int s = atomicAdd(&cnt[grow * NC16 + c16], 1);
                        if (s < SLOTS) cand[((size_t)grow * NC16 + c16) * SLOTS + s] = c16 * 64 + ct * 16 + lr;
                    }
                }
            }
    }
}

// ---------------- exact rescore (np/OpenBLAS-exact dots, first-index ties) ----
__global__ __launch_bounds__(256) void rescore_kernel(
    const float* __restrict__ z, const float* __restrict__ e,
    const float* __restrict__ sz, const float* __restrict__ se,
    const float* __restrict__ epsr, const float* __restrict__ cqmin,
    const int* __restrict__ cnt, const int* __restrict__ cand,
    int* __restrict__ out_idx, float* __restrict__ out_idx_f) {
    const int row = blockIdx.x * 256 + threadIdx.x;
    float gmin = __builtin_inff();
#pragma unroll
    for (int c16 = 0; c16 < NC16; ++c16)
        gmin = fminf(gmin, cqmin[(size_t)row * NC16 + c16]);
    const float thr = fmaf(2.0f, epsr[row], gmin);

    int ncand = 0, first_c = 0;
    bool need_scan = false;
#pragma unroll
    for (int c16 = 0; c16 < NC16; ++c16) {
        if (cqmin[(size_t)row * NC16 + c16] <= thr) {
            int n = cnt[(size_t)row * NC16 + c16];
            if (n > SLOTS) { need_scan = true; }
            else {
                for (int s = 0; s < n; ++s) {
                    int c = cand[((size_t)row * NC16 + c16) * SLOTS + s];
                    if (ncand == 0) first_c = c;
                    ++ncand;
                }
            }
        }
    }
    int bi;
    if (!need_scan && ncand == 1) {
        bi = first_c;
    } else {
        const float szr = sz[row];
        const float* zr = z + (size_t)row * ZDIM;
        float bd = __builtin_inff();
        bi = 0x7fffffff;
#pragma unroll 1
        for (int c16 = 0; c16 < NC16; ++c16) {
            if (cqmin[(size_t)row * NC16 + c16] > thr) continue;
            int n = cnt[(size_t)row * NC16 + c16];
            if (n > SLOTS) {
                for (int c = c16 * 64; c < c16 * 64 + 64; ++c) {
                    const float* er = e + (size_t)c * ZDIM;
                    float m = 0.0f;
                    for (int k = 0; k < ZDIM; ++k) m = fmaf(zr[k], er[k], m);
                    float d = __fsub_rn(__fadd_rn(szr, se[c]), 2.0f * m);
                    if (d < bd || (d == bd && c < bi)) { bd = d; bi = c; }
                }
            } else {
                for (int s = 0; s < n; ++s) {
                    int c = cand[((size_t)row * NC16 + c16) * SLOTS + s];
                    const float* er = e + (size_t)c * ZDIM;
                    float m = 0.0f;
                    for (int k = 0; k < ZDIM; ++k) m = fmaf(zr[k], er[k], m);
                    float d = __fsub_rn(__fadd_rn(szr, se[c]), 2.0f * m);
                    if (d < bd || (d == bd && c < bi)) { bd = d; bi = c; }
                }
            }
        }
    }
    out_idx[row] = bi;
    out_idx_f[row] = (float)bi;
}

// ---------------- z_q_st + loss partial (no atomics) ----------------
__global__ __launch_bounds__(256) void zq_loss_kernel(
    const float* __restrict__ z, const float* __restrict__ e,
    const int* __restrict__ idx, float* __restrict__ out,
    double* __restrict__ partial) {
    const int tid = threadIdx.x;
    const int rl  = tid >> 6;
    const int ln  = tid & 63;
    const int row0 = blockIdx.x * 32;

    float acc = 0.0f;
#pragma unroll
    for (int it = 0; it < 8; ++it) {
        int row = row0 + it * 4 + rl;
        int code = idx[row];
        const float4 vz = *(const float4*)(z + (size_t)row  * ZDIM + ln * 4);
        const float4 vq = *(const float4*)(e + (size_t)code * ZDIM + ln * 4);
        float4 o;
        float dx = __fsub_rn(vq.x, vz.x);
        float dy = __fsub_rn(vq.y, vz.y);
        float dz_ = __fsub_rn(vq.z, vz.z);
        float dw = __fsub_rn(vq.w, vz.w);
        o.x = __fadd_rn(vz.x, dx);
        o.y = __fadd_rn(vz.y, dy);
        o.z = __fadd_rn(vz.z, dz_);
        o.w = __fadd_rn(vz.w, dw);
        *(float4*)(out + (size_t)row * ZDIM + ln * 4) = o;
        acc = __fadd_rn(acc, __fmul_rn(dx, dx));
        acc = __fadd_rn(acc, __fmul_rn(dy, dy));
        acc = __fadd_rn(acc, __fmul_rn(dz_, dz_));
        acc = __fadd_rn(acc, __fmul_rn(dw, dw));
    }

    __shared__ double red[256];
    red[tid] = (double)acc;
    __syncthreads();
#pragma unroll
    for (int s = 128; s > 0; s >>= 1) {
        if (tid < s) red[tid] += red[tid + s];
        __syncthreads();
    }
    if (tid == 0) partial[blockIdx.x] = red[0];
}

__global__ __launch_bounds__(256) void loss_final_kernel(
    const double* __restrict__ partial, float* __restrict__ out_loss) {
    const int tid = threadIdx.x;
    double s = 0.0;
    for (int i = tid; i < ZQ_BLOCKS; i += 256) s += partial[i];
    __shared__ double red[256];
    red[tid] = s;
    __syncthreads();
#pragma unroll
    for (int st = 128; st > 0; st >>= 1) {
        if (tid < st) red[tid] += red[tid + st];
        __syncthreads();
    }
    if (tid == 0) {
        double M = red[0] / 16777216.0;
        float m32 = (float)M;
        out_loss[0] = __fadd_rn(m32, __fmul_rn(0.25f, m32));
    }
}

extern "C" void kernel_launch(void* const* d_in, const int* in_sizes, int n_in,
                              void* d_out, int out_size, void* d_ws, size_t ws_size,
                              hipStream_t stream) {
    const float* z = (const float*)d_in[0];
    const float* e = (const float*)d_in[1];
    float* out = (float*)d_out;
    char* ws = (char*)d_ws;

    size_t off = 0;
    double* partial = (double*)(ws + off); off += ZQ_BLOCKS * sizeof(double);       // 16 KB
    float*  sz      = (float*) (ws + off); off += (size_t)N_ROWS * 4;               // 256 KB
    float*  epsr    = (float*) (ws + off); off += (size_t)N_ROWS * 4;               // 256 KB
    float*  se      = (float*) (ws + off); off += (size_t)KCODES * 4;               // 4 KB
    int*    idx     = (int*)   (ws + off); off += (size_t)N_ROWS * 4;               // 256 KB
    u16*    ehf     = (u16*)   (ws + off); off += (size_t)KCODES * ZDIM * 2;        // 512 KB
    float*  cqmin   = (float*) (ws + off); off += (size_t)N_ROWS * NC16 * 4;        // 4 MB
    int*    cnt     = (int*)   (ws + off); off += (size_t)N_ROWS * NC16 * 4;        // 4 MB
    int*    cand    = (int*)   (ws + off); off += (size_t)N_ROWS * NC16 * SLOTS * 4;// 8 MB

    u16* zh = (u16*)out;   // bf16 z in d_out z_q region; zq_loss overwrites later

    hipMemsetAsync(cnt, 0, (size_t)N_ROWS * NC16 * 4, stream);
    split_z_kernel<<<8192, 256, 0, stream>>>(z, zh);
    split_e_kernel<<<256, 256, 0, stream>>>(e, ehf);
    rowsq_eps_kernel<<<N_ROWS / 256, 256, 0, stream>>>(z, sz, epsr);
    rowsq_kernel<<<KCODES / 256, 256, 0, stream>>>(e, se, KCODES);
    mfma_argmin_kernel<<<1024, 256, 0, stream>>>(zh, ehf, sz, se, epsr, cqmin, cnt, cand);
    rescore_kernel<<<N_ROWS / 256, 256, 0, stream>>>(z, e, sz, se, epsr, cqmin, cnt, cand, idx, out + IDX_OFF);
    zq_loss_kernel<<<ZQ_BLOCKS, 256, 0, stream>>>(z, e, idx, out, partial);
    loss_final_kernel<<<1, 256, 0, stream>>>(partial, out + LOSS_OFF);
}

// Round 13
// 1075.233 us; speedup vs baseline: 1.2351x; 1.2351x over previous
//
#include <hip/hip_runtime.h>
#include <hip/hip_bf16.h>
#include <math.h>

#define N_ROWS 65536
#define ZDIM   256
#define KCODES 1024
#define IDX_OFF  (N_ROWS * ZDIM)        // 16777216
#define LOSS_OFF (IDX_OFF + N_ROWS)     // 16842752
#define ZQ_BLOCKS 2048
#define SLOTS 10
#define NC16 16                          // cqmin granularity: 16 chunks of 64
#define NC8  8                           // cand-list granularity: 8 chunks of 128

typedef unsigned int u32;
typedef unsigned short u16;
typedef __attribute__((ext_vector_type(8))) short bfrag;   // 8 bf16 (4 VGPR)
typedef __attribute__((ext_vector_type(4))) float ffrag;   // 4 fp32 acc

__device__ __forceinline__ u16 f2bf(float x) {
    __hip_bfloat16 h = __float2bfloat16(x);      // RN
    union { __hip_bfloat16 h; u16 u; } c; c.h = h; return c.u;
}

// ---------------- numpy-pairwise helpers (256 cols) ----------------
__device__ __forceinline__ float np_pw128_sq(const float* __restrict__ p) {
    float r[8];
#pragma unroll
    for (int j = 0; j < 8; ++j) r[j] = __fmul_rn(p[j], p[j]);
    for (int i = 8; i < 128; i += 8) {
#pragma unroll
        for (int j = 0; j < 8; ++j)
            r[j] = __fadd_rn(r[j], __fmul_rn(p[i + j], p[i + j]));
    }
    float a = __fadd_rn(__fadd_rn(r[0], r[1]), __fadd_rn(r[2], r[3]));
    float b = __fadd_rn(__fadd_rn(r[4], r[5]), __fadd_rn(r[6], r[7]));
    return __fadd_rn(a, b);
}

__device__ __forceinline__ float pw128_abs(const float* __restrict__ p) {
    float r[8];
#pragma unroll
    for (int j = 0; j < 8; ++j) r[j] = fabsf(p[j]);
    for (int i = 8; i < 128; i += 8) {
#pragma unroll
        for (int j = 0; j < 8; ++j) r[j] += fabsf(p[i + j]);
    }
    return ((r[0] + r[1]) + (r[2] + r[3])) + ((r[4] + r[5]) + (r[6] + r[7]));
}

// exact OpenBLAS-order dot, float4 loads (same fmaf sequence, 4x fewer loads)
__device__ __forceinline__ float exact_dot(const float* __restrict__ zr,
                                           const float* __restrict__ er) {
    float m = 0.0f;
#pragma unroll 4
    for (int k = 0; k < ZDIM; k += 4) {
        float4 a = *(const float4*)(zr + k);
        float4 b = *(const float4*)(er + k);
        m = fmaf(a.x, b.x, m);
        m = fmaf(a.y, b.y, m);
        m = fmaf(a.z, b.z, m);
        m = fmaf(a.w, b.w, m);
    }
    return m;
}

__global__ void rowsq_kernel(const float* __restrict__ x, float* __restrict__ s, int nrows) {
    int r = blockIdx.x * blockDim.x + threadIdx.x;
    if (r >= nrows) return;
    const float* p = x + (size_t)r * ZDIM;
    s[r] = __fadd_rn(np_pw128_sq(p), np_pw128_sq(p + 128));
}

// sz (np-exact) + per-row rigorous eps for the 1-pass bf16 bound
__global__ void rowsq_eps_kernel(const float* __restrict__ x, float* __restrict__ s,
                                 float* __restrict__ epsr) {
    int r = blockIdx.x * blockDim.x + threadIdx.x;
    const float* p = x + (size_t)r * ZDIM;
    s[r] = __fadd_rn(np_pw128_sq(p), np_pw128_sq(p + 128));
    float S1 = pw128_abs(p) + pw128_abs(p + 128);
    epsr[r] = fmaf(S1, 8.4e-6f, 1.2e-4f);
}

// ---------------- z -> bf16 (RN), row-major, into d_out z_q region ----------
__global__ __launch_bounds__(256) void split_z_kernel(
    const float* __restrict__ z, u16* __restrict__ zh) {
    int t = blockIdx.x * 256 + threadIdx.x;
    int i = t * 8;
    float4 a = *(const float4*)(z + i);
    float4 b = *(const float4*)(z + i + 4);
    uint4 w;
    w.x = ((u32)f2bf(a.y) << 16) | f2bf(a.x);
    w.y = ((u32)f2bf(a.w) << 16) | f2bf(a.z);
    w.z = ((u32)f2bf(b.y) << 16) | f2bf(b.x);
    w.w = ((u32)f2bf(b.w) << 16) | f2bf(b.z);
    *(uint4*)(zh + i) = w;
}

// ---------------- e -> bf16, FRAGMENT-MAJOR layout ----------------
// B-fragment for (c16, kc, ct) is 1024B contiguous: 64 lanes x 8 shorts.
// lane = lk*16 + lr holds code c16*64+ct*16+lr, dims kc*32+lk*8 .. +7.
__global__ __launch_bounds__(256) void split_e_kernel(
    const float* __restrict__ e, u16* __restrict__ ehf) {
    int t = blockIdx.x * 256 + threadIdx.x;      // 65536 threads
    int c = t >> 6, kq = t & 63;                 // dims kq*4 .. +3
    float4 v = *(const float4*)(e + (size_t)c * ZDIM + kq * 4);
    ushort4 h;
    h.x = f2bf(v.x); h.y = f2bf(v.y); h.z = f2bf(v.z); h.w = f2bf(v.w);
    int c16 = c >> 6, ct = (c >> 4) & 3, lr = c & 15;
    int kc = kq >> 3, lk = (kq >> 1) & 3;        // (k>>3)&3 with k=kq*4
    int lane = lk * 16 + lr;
    size_t base = ((size_t)((c16 * 8 + kc) * 4 + ct) * 64 + lane) * 8 + ((kq * 4) & 7);
    *(ushort4*)(ehf + base) = h;
}

// ---------------- wave-autonomous 1-pass MFMA + candidate emission ----------
// (structure identical to r12 = known-correct; only cand/cnt indexing moved
// from c16 (64-code) to c8 (128-code) granularity, SLOTS=10)
__global__ __launch_bounds__(256) void mfma_argmin_kernel(
    const u16* __restrict__ zh, const u16* __restrict__ ehf,
    const float* __restrict__ sz, const float* __restrict__ se,
    const float* __restrict__ epsr, float* __restrict__ cqmin,
    int* __restrict__ cnt, int* __restrict__ cand) {
    __shared__ float sse[KCODES];                     // 4 KB
    const int tid = threadIdx.x;
    const int w = tid >> 6, lane = tid & 63;
    const int lr = lane & 15, lk = lane >> 4;
    const int rp = blockIdx.x >> 1, cp = blockIdx.x & 1;
    const int wr0 = rp * 128 + w * 32;

    *(float4*)(sse + tid * 4) = *(const float4*)(se + tid * 4);
    __syncthreads();                                  // only barrier (sse init)

    float szv[2][4], epsv[2][4];
#pragma unroll
    for (int rt = 0; rt < 2; ++rt)
#pragma unroll
        for (int j = 0; j < 4; ++j) {
            szv[rt][j]  = sz[wr0 + rt * 16 + lk * 4 + j];
            epsv[rt][j] = epsr[wr0 + rt * 16 + lk * 4 + j];
        }

    bfrag A[2][8];
#pragma unroll
    for (int rt = 0; rt < 2; ++rt)
#pragma unroll
        for (int kc = 0; kc < 8; ++kc)
            A[rt][kc] = *(const bfrag*)(zh + (size_t)(wr0 + rt * 16 + lr) * ZDIM + kc * 32 + lk * 8);

#pragma unroll 1
    for (int cc = 0; cc < 8; ++cc) {
        const int c16 = cp * 8 + cc;
        const int c8 = c16 >> 1;
        ffrag acc[2][4];
#pragma unroll
        for (int rt = 0; rt < 2; ++rt)
#pragma unroll
            for (int ct = 0; ct < 4; ++ct) acc[rt][ct] = (ffrag)(0.0f);

        // B fragments: double reg-buffer, static indices (rule #20)
        bfrag B0[4], B1[4];
        {
            const u16* bb = ehf + (size_t)((c16 * 8 + 0) * 4) * 512 + lane * 8;
#pragma unroll
            for (int ct = 0; ct < 4; ++ct) B0[ct] = *(const bfrag*)(bb + ct * 512);
        }
#pragma unroll
        for (int kc = 0; kc < 8; ++kc) {
            if (kc < 7) {
                const u16* bb = ehf + (size_t)((c16 * 8 + kc + 1) * 4) * 512 + lane * 8;
                if (kc & 1) {
#pragma unroll
                    for (int ct = 0; ct < 4; ++ct) B0[ct] = *(const bfrag*)(bb + ct * 512);
                } else {
#pragma unroll
                    for (int ct = 0; ct < 4; ++ct) B1[ct] = *(const bfrag*)(bb + ct * 512);
                }
            }
            if (kc & 1) {
#pragma unroll
                for (int ct = 0; ct < 4; ++ct) {
                    acc[0][ct] = __builtin_amdgcn_mfma_f32_16x16x32_bf16(A[0][kc], B1[ct], acc[0][ct], 0, 0, 0);
                    acc[1][ct] = __builtin_amdgcn_mfma_f32_16x16x32_bf16(A[1][kc], B1[ct], acc[1][ct], 0, 0, 0);
                }
            } else {
#pragma unroll
                for (int ct = 0; ct < 4; ++ct) {
                    acc[0][ct] = __builtin_amdgcn_mfma_f32_16x16x32_bf16(A[0][kc], B0[ct], acc[0][ct], 0, 0, 0);
                    acc[1][ct] = __builtin_amdgcn_mfma_f32_16x16x32_bf16(A[1][kc], B0[ct], acc[1][ct], 0, 0, 0);
                }
            }
        }

        // ---- epilogue for c16: d~ = fl(fl(sz+se) - 2*m~) ----
        float rmin[2][4];
#pragma unroll
        for (int rt = 0; rt < 2; ++rt)
#pragma unroll
            for (int j = 0; j < 4; ++j) rmin[rt][j] = __builtin_inff();
#pragma unroll
        for (int rt = 0; rt < 2; ++rt)
#pragma unroll
            for (int ct = 0; ct < 4; ++ct) {
                float sec = sse[c16 * 64 + ct * 16 + lr];
#pragma unroll
                for (int j = 0; j < 4; ++j) {
                    float dd = __fsub_rn(__fadd_rn(szv[rt][j], sec), 2.0f * acc[rt][ct][j]);
                    rmin[rt][j] = fminf(rmin[rt][j], dd);
                }
            }
#pragma unroll
        for (int m = 1; m < 16; m <<= 1)
#pragma unroll
            for (int rt = 0; rt < 2; ++rt)
#pragma unroll
                for (int j = 0; j < 4; ++j)
                    rmin[rt][j] = fminf(rmin[rt][j], __shfl_xor(rmin[rt][j], m, 64));
        if (lr == 0) {
#pragma unroll
            for (int rt = 0; rt < 2; ++rt)
#pragma unroll
                for (int j = 0; j < 4; ++j)
                    cqmin[(size_t)(wr0 + rt * 16 + lk * 4 + j) * NC16 + c16] = rmin[rt][j];
        }
#pragma unroll
        for (int rt = 0; rt < 2; ++rt)
#pragma unroll
            for (int j = 0; j < 4; ++j) {
                const float thr = fmaf(2.0f, epsv[rt][j], rmin[rt][j]);
                const int grow = wr0 + rt * 16 + lk * 4 + j;
#pragma unroll
                for (int ct = 0; ct < 4; ++ct) {
                    float dd = __fsub_rn(__fadd_rn(szv[rt][j], sse[c16 * 64 + ct * 16 + lr]),
                                         2.0f * acc[rt][ct][j]);
                    if (dd <= thr) {
                        int s = atomicAdd(&cnt[grow * NC8 + c8], 1);
                        if (s < SLOTS) cand[((size_t)grow * NC8 + c8) * SLOTS + s] = c16 * 64 + ct * 16 + lr;
                    }
                }
            }
    }
}

// ---------------- exact rescore ----------------
// gmin over 16 cqmins; c8 qualifies iff min(cqmin[2c8],cqmin[2c8+1]) <= thr.
// Superset proof: relevant code c (d~ <= gmin+2eps) has chunk rmin >= gmin
// -> d~ <= rmin+2eps -> emitted; its c8 qualifies. Single candidate -> done;
// else exact vectorized OpenBLAS-order dots, lexicographic (d, idx) min.
__global__ __launch_bounds__(256) void rescore_kernel(
    const float* __restrict__ z, const float* __restrict__ e,
    const float* __restrict__ sz, const float* __restrict__ se,
    const float* __restrict__ epsr, const float* __restrict__ cqmin,
    const int* __restrict__ cnt, const int* __restrict__ cand,
    int* __restrict__ out_idx, float* __restrict__ out_idx_f) {
    const int row = blockIdx.x * 256 + threadIdx.x;
    float gmin = __builtin_inff();
#pragma unroll
    for (int c16 = 0; c16 < NC16; ++c16)
        gmin = fminf(gmin, cqmin[(size_t)row * NC16 + c16]);
    const float thr = fmaf(2.0f, epsr[row], gmin);

    int ncand = 0, first_c = 0;
    bool need_scan = false;
#pragma unroll
    for (int c8 = 0; c8 < NC8; ++c8) {
        float cm = fminf(cqmin[(size_t)row * NC16 + 2 * c8],
                         cqmin[(size_t)row * NC16 + 2 * c8 + 1]);
        if (cm <= thr) {
            int n = cnt[(size_t)row * NC8 + c8];
            if (n > SLOTS) { need_scan = true; }
            else {
                for (int s = 0; s < n; ++s) {
                    int c = cand[((size_t)row * NC8 + c8) * SLOTS + s];
                    if (ncand == 0) first_c = c;
                    ++ncand;
                }
            }
        }
    }
    int bi;
    if (!need_scan && ncand == 1) {
        bi = first_c;
    } else {
        const float szr = sz[row];
        const float* zr = z + (size_t)row * ZDIM;
        float bd = __builtin_inff();
        bi = 0x7fffffff;
#pragma unroll 1
        for (int c8 = 0; c8 < NC8; ++c8) {
            float cm = fminf(cqmin[(size_t)row * NC16 + 2 * c8],
                             cqmin[(size_t)row * NC16 + 2 * c8 + 1]);
            if (cm > thr) continue;
            int n = cnt[(size_t)row * NC8 + c8];
            if (n > SLOTS) {
#pragma unroll 1
                for (int c = c8 * 128; c < c8 * 128 + 128; ++c) {
                    float m = exact_dot(zr, e + (size_t)c * ZDIM);
                    float d = __fsub_rn(__fadd_rn(szr, se[c]), 2.0f * m);
                    if (d < bd || (d == bd && c < bi)) { bd = d; bi = c; }
                }
            } else {
#pragma unroll 1
                for (int s = 0; s < n; ++s) {
                    int c = cand[((size_t)row * NC8 + c8) * SLOTS + s];
                    float m = exact_dot(zr, e + (size_t)c * ZDIM);
                    float d = __fsub_rn(__fadd_rn(szr, se[c]), 2.0f * m);
                    if (d < bd || (d == bd && c < bi)) { bd = d; bi = c; }
                }
            }
        }
    }
    out_idx[row] = bi;
    out_idx_f[row] = (float)bi;
}

// ---------------- z_q_st + loss partial (no atomics) ----------------
__global__ __launch_bounds__(256) void zq_loss_kernel(
    const float* __restrict__ z, const float* __restrict__ e,
    const int* __restrict__ idx, float* __restrict__ out,
    double* __restrict__ partial) {
    const int tid = threadIdx.x;
    const int rl  = tid >> 6;
    const int ln  = tid & 63;
    const int row0 = blockIdx.x * 32;

    float acc = 0.0f;
#pragma unroll
    for (int it = 0; it < 8; ++it) {
        int row = row0 + it * 4 + rl;
        int code = idx[row];
        const float4 vz = *(const float4*)(z + (size_t)row  * ZDIM + ln * 4);
        const float4 vq = *(const float4*)(e + (size_t)code * ZDIM + ln * 4);
        float4 o;
        float dx = __fsub_rn(vq.x, vz.x);
        float dy = __fsub_rn(vq.y, vz.y);
        float dz_ = __fsub_rn(vq.z, vz.z);
        float dw = __fsub_rn(vq.w, vz.w);
        o.x = __fadd_rn(vz.x, dx);
        o.y = __fadd_rn(vz.y, dy);
        o.z = __fadd_rn(vz.z, dz_);
        o.w = __fadd_rn(vz.w, dw);
        *(float4*)(out + (size_t)row * ZDIM + ln * 4) = o;
        acc = __fadd_rn(acc, __fmul_rn(dx, dx));
        acc = __fadd_rn(acc, __fmul_rn(dy, dy));
        acc = __fadd_rn(acc, __fmul_rn(dz_, dz_));
        acc = __fadd_rn(acc, __fmul_rn(dw, dw));
    }

    __shared__ double red[256];
    red[tid] = (double)acc;
    __syncthreads();
#pragma unroll
    for (int s = 128; s > 0; s >>= 1) {
        if (tid < s) red[tid] += red[tid + s];
        __syncthreads();
    }
    if (tid == 0) partial[blockIdx.x] = red[0];
}

__global__ __launch_bounds__(256) void loss_final_kernel(
    const double* __restrict__ partial, float* __restrict__ out_loss) {
    const int tid = threadIdx.x;
    double s = 0.0;
    for (int i = tid; i < ZQ_BLOCKS; i += 256) s += partial[i];
    __shared__ double red[256];
    red[tid] = s;
    __syncthreads();
#pragma unroll
    for (int st = 128; st > 0; st >>= 1) {
        if (tid < st) red[tid] += red[tid + st];
        __syncthreads();
    }
    if (tid == 0) {
        double M = red[0] / 16777216.0;
        float m32 = (float)M;
        out_loss[0] = __fadd_rn(m32, __fmul_rn(0.25f, m32));
    }
}

extern "C" void kernel_launch(void* const* d_in, const int* in_sizes, int n_in,
                              void* d_out, int out_size, void* d_ws, size_t ws_size,
                              hipStream_t stream) {
    const float* z = (const float*)d_in[0];
    const float* e = (const float*)d_in[1];
    float* out = (float*)d_out;
    char* ws = (char*)d_ws;

    size_t off = 0;
    double* partial = (double*)(ws + off); off += ZQ_BLOCKS * sizeof(double);       // 16 KB
    float*  sz      = (float*) (ws + off); off += (size_t)N_ROWS * 4;               // 256 KB
    float*  epsr    = (float*) (ws + off); off += (size_t)N_ROWS * 4;               // 256 KB
    float*  se      = (float*) (ws + off); off += (size_t)KCODES * 4;               // 4 KB
    int*    idx     = (int*)   (ws + off); off += (size_t)N_ROWS * 4;               // 256 KB
    u16*    ehf     = (u16*)   (ws + off); off += (size_t)KCODES * ZDIM * 2;        // 512 KB
    float*  cqmin   = (float*) (ws + off); off += (size_t)N_ROWS * NC16 * 4;        // 4 MB
    int*    cnt     = (int*)   (ws + off); off += (size_t)N_ROWS * NC8 * 4;         // 2 MB
    int*    cand    = (int*)   (ws + off); off += (size_t)N_ROWS * NC8 * SLOTS * 4; // 20 MB

    u16* zh = (u16*)out;   // bf16 z in d_out z_q region; zq_loss overwrites later

    hipMemsetAsync(cnt, 0, (size_t)N_ROWS * NC8 * 4, stream);
    split_z_kernel<<<8192, 256, 0, stream>>>(z, zh);
    split_e_kernel<<<256, 256, 0, stream>>>(e, ehf);
    rowsq_eps_kernel<<<N_ROWS / 256, 256, 0, stream>>>(z, sz, epsr);
    rowsq_kernel<<<KCODES / 256, 256, 0, stream>>>(e, se, KCODES);
    mfma_argmin_kernel<<<1024, 256, 0, stream>>>(zh, ehf, sz, se, epsr, cqmin, cnt, cand);
    rescore_kernel<<<N_ROWS / 256, 256, 0, stream>>>(z, e, sz, se, epsr, cqmin, cnt, cand, idx, out + IDX_OFF);
    zq_loss_kernel<<<ZQ_BLOCKS, 256, 0, stream>>>(z, e, idx, out, partial);
    loss_final_kernel<<<1, 256, 0, stream>>>(partial, out + LOSS_OFF);
}

// Round 14
// 835.430 us; speedup vs baseline: 1.5896x; 1.2870x over previous
//
#include <hip/hip_runtime.h>
#include <hip/hip_bf16.h>
#include <math.h>

#define N_ROWS 65536
#define ZDIM   256
#define KCODES 1024
#define IDX_OFF  (N_ROWS * ZDIM)        // 16777216
#define LOSS_OFF (IDX_OFF + N_ROWS)     // 16842752
#define ZQ_BLOCKS 2048
#define SLOTS 4
#define NC16 16                          // cqmin granularity: 16 chunks of 64
#define NC8  8                           // cand-list granularity: 8 chunks of 128

typedef unsigned int u32;
typedef unsigned short u16;
typedef __attribute__((ext_vector_type(8))) short bfrag;   // 8 bf16 (4 VGPR)
typedef __attribute__((ext_vector_type(4))) float ffrag;   // 4 fp32 acc

__device__ __forceinline__ u16 f2bf(float x) {
    __hip_bfloat16 h = __float2bfloat16(x);      // RN
    union { __hip_bfloat16 h; u16 u; } c; c.h = h; return c.u;
}

// ---------------- numpy-pairwise helpers (256 cols) ----------------
__device__ __forceinline__ float np_pw128_sq(const float* __restrict__ p) {
    float r[8];
#pragma unroll
    for (int j = 0; j < 8; ++j) r[j] = __fmul_rn(p[j], p[j]);
    for (int i = 8; i < 128; i += 8) {
#pragma unroll
        for (int j = 0; j < 8; ++j)
            r[j] = __fadd_rn(r[j], __fmul_rn(p[i + j], p[i + j]));
    }
    float a = __fadd_rn(__fadd_rn(r[0], r[1]), __fadd_rn(r[2], r[3]));
    float b = __fadd_rn(__fadd_rn(r[4], r[5]), __fadd_rn(r[6], r[7]));
    return __fadd_rn(a, b);
}

__device__ __forceinline__ float pw128_abs(const float* __restrict__ p) {
    float r[8];
#pragma unroll
    for (int j = 0; j < 8; ++j) r[j] = fabsf(p[j]);
    for (int i = 8; i < 128; i += 8) {
#pragma unroll
        for (int j = 0; j < 8; ++j) r[j] += fabsf(p[i + j]);
    }
    return ((r[0] + r[1]) + (r[2] + r[3])) + ((r[4] + r[5]) + (r[6] + r[7]));
}

// exact OpenBLAS-order dot, float4 loads (same fmaf sequence, 4x fewer loads)
__device__ __forceinline__ float exact_dot(const float* __restrict__ zr,
                                           const float* __restrict__ er) {
    float m = 0.0f;
#pragma unroll 4
    for (int k = 0; k < ZDIM; k += 4) {
        float4 a = *(const float4*)(zr + k);
        float4 b = *(const float4*)(er + k);
        m = fmaf(a.x, b.x, m);
        m = fmaf(a.y, b.y, m);
        m = fmaf(a.z, b.z, m);
        m = fmaf(a.w, b.w, m);
    }
    return m;
}

__global__ void rowsq_kernel(const float* __restrict__ x, float* __restrict__ s, int nrows) {
    int r = blockIdx.x * blockDim.x + threadIdx.x;
    if (r >= nrows) return;
    const float* p = x + (size_t)r * ZDIM;
    s[r] = __fadd_rn(np_pw128_sq(p), np_pw128_sq(p + 128));
}

// sz (np-exact) + per-row rigorous eps for the 1-pass bf16 bound
__global__ void rowsq_eps_kernel(const float* __restrict__ x, float* __restrict__ s,
                                 float* __restrict__ epsr) {
    int r = blockIdx.x * blockDim.x + threadIdx.x;
    const float* p = x + (size_t)r * ZDIM;
    s[r] = __fadd_rn(np_pw128_sq(p), np_pw128_sq(p + 128));
    float S1 = pw128_abs(p) + pw128_abs(p + 128);
    epsr[r] = fmaf(S1, 8.4e-6f, 1.2e-4f);
}

// ---------------- z -> bf16 (RN), row-major, into d_out z_q region ----------
__global__ __launch_bounds__(256) void split_z_kernel(
    const float* __restrict__ z, u16* __restrict__ zh) {
    int t = blockIdx.x * 256 + threadIdx.x;
    int i = t * 8;
    float4 a = *(const float4*)(z + i);
    float4 b = *(const float4*)(z + i + 4);
    uint4 w;
    w.x = ((u32)f2bf(a.y) << 16) | f2bf(a.x);
    w.y = ((u32)f2bf(a.w) << 16) | f2bf(a.z);
    w.z = ((u32)f2bf(b.y) << 16) | f2bf(b.x);
    w.w = ((u32)f2bf(b.w) << 16) | f2bf(b.z);
    *(uint4*)(zh + i) = w;
}

// ---------------- e -> bf16, FRAGMENT-MAJOR layout ----------------
__global__ __launch_bounds__(256) void split_e_kernel(
    const float* __restrict__ e, u16* __restrict__ ehf) {
    int t = blockIdx.x * 256 + threadIdx.x;      // 65536 threads
    int c = t >> 6, kq = t & 63;                 // dims kq*4 .. +3
    float4 v = *(const float4*)(e + (size_t)c * ZDIM + kq * 4);
    ushort4 h;
    h.x = f2bf(v.x); h.y = f2bf(v.y); h.z = f2bf(v.z); h.w = f2bf(v.w);
    int c16 = c >> 6, ct = (c >> 4) & 3, lr = c & 15;
    int kc = kq >> 3, lk = (kq >> 1) & 3;
    int lane = lk * 16 + lr;
    size_t base = ((size_t)((c16 * 8 + kc) * 4 + ct) * 64 + lane) * 8 + ((kq * 4) & 7);
    *(ushort4*)(ehf + base) = h;
}

// ---------------- wave-autonomous 1-pass MFMA + candidate emission ----------
// r12/r13-verified structure; emission now stores (d~, code) pairs.
__global__ __launch_bounds__(256) void mfma_argmin_kernel(
    const u16* __restrict__ zh, const u16* __restrict__ ehf,
    const float* __restrict__ sz, const float* __restrict__ se,
    const float* __restrict__ epsr, float* __restrict__ cqmin,
    int* __restrict__ cnt, float* __restrict__ cand_d, int* __restrict__ cand_i) {
    __shared__ float sse[KCODES];                     // 4 KB
    const int tid = threadIdx.x;
    const int w = tid >> 6, lane = tid & 63;
    const int lr = lane & 15, lk = lane >> 4;
    const int rp = blockIdx.x >> 1, cp = blockIdx.x & 1;
    const int wr0 = rp * 128 + w * 32;

    *(float4*)(sse + tid * 4) = *(const float4*)(se + tid * 4);
    __syncthreads();                                  // only barrier (sse init)

    float szv[2][4], epsv[2][4];
#pragma unroll
    for (int rt = 0; rt < 2; ++rt)
#pragma unroll
        for (int j = 0; j < 4; ++j) {
            szv[rt][j]  = sz[wr0 + rt * 16 + lk * 4 + j];
            epsv[rt][j] = epsr[wr0 + rt * 16 + lk * 4 + j];
        }

    bfrag A[2][8];
#pragma unroll
    for (int rt = 0; rt < 2; ++rt)
#pragma unroll
        for (int kc = 0; kc < 8; ++kc)
            A[rt][kc] = *(const bfrag*)(zh + (size_t)(wr0 + rt * 16 + lr) * ZDIM + kc * 32 + lk * 8);

#pragma unroll 1
    for (int cc = 0; cc < 8; ++cc) {
        const int c16 = cp * 8 + cc;
        const int c8 = c16 >> 1;
        ffrag acc[2][4];
#pragma unroll
        for (int rt = 0; rt < 2; ++rt)
#pragma unroll
            for (int ct = 0; ct < 4; ++ct) acc[rt][ct] = (ffrag)(0.0f);

        bfrag B0[4], B1[4];
        {
            const u16* bb = ehf + (size_t)((c16 * 8 + 0) * 4) * 512 + lane * 8;
#pragma unroll
            for (int ct = 0; ct < 4; ++ct) B0[ct] = *(const bfrag*)(bb + ct * 512);
        }
#pragma unroll
        for (int kc = 0; kc < 8; ++kc) {
            if (kc < 7) {
                const u16* bb = ehf + (size_t)((c16 * 8 + kc + 1) * 4) * 512 + lane * 8;
                if (kc & 1) {
#pragma unroll
                    for (int ct = 0; ct < 4; ++ct) B0[ct] = *(const bfrag*)(bb + ct * 512);
                } else {
#pragma unroll
                    for (int ct = 0; ct < 4; ++ct) B1[ct] = *(const bfrag*)(bb + ct * 512);
                }
            }
            if (kc & 1) {
#pragma unroll
                for (int ct = 0; ct < 4; ++ct) {
                    acc[0][ct] = __builtin_amdgcn_mfma_f32_16x16x32_bf16(A[0][kc], B1[ct], acc[0][ct], 0, 0, 0);
                    acc[1][ct] = __builtin_amdgcn_mfma_f32_16x16x32_bf16(A[1][kc], B1[ct], acc[1][ct], 0, 0, 0);
                }
            } else {
#pragma unroll
                for (int ct = 0; ct < 4; ++ct) {
                    acc[0][ct] = __builtin_amdgcn_mfma_f32_16x16x32_bf16(A[0][kc], B0[ct], acc[0][ct], 0, 0, 0);
                    acc[1][ct] = __builtin_amdgcn_mfma_f32_16x16x32_bf16(A[1][kc], B0[ct], acc[1][ct], 0, 0, 0);
                }
            }
        }

        // ---- epilogue for c16: d~ = fl(fl(sz+se) - 2*m~) ----
        float rmin[2][4];
#pragma unroll
        for (int rt = 0; rt < 2; ++rt)
#pragma unroll
            for (int j = 0; j < 4; ++j) rmin[rt][j] = __builtin_inff();
#pragma unroll
        for (int rt = 0; rt < 2; ++rt)
#pragma unroll
            for (int ct = 0; ct < 4; ++ct) {
                float sec = sse[c16 * 64 + ct * 16 + lr];
#pragma unroll
                for (int j = 0; j < 4; ++j) {
                    float dd = __fsub_rn(__fadd_rn(szv[rt][j], sec), 2.0f * acc[rt][ct][j]);
                    rmin[rt][j] = fminf(rmin[rt][j], dd);
                }
            }
#pragma unroll
        for (int m = 1; m < 16; m <<= 1)
#pragma unroll
            for (int rt = 0; rt < 2; ++rt)
#pragma unroll
                for (int j = 0; j < 4; ++j)
                    rmin[rt][j] = fminf(rmin[rt][j], __shfl_xor(rmin[rt][j], m, 64));
        if (lr == 0) {
#pragma unroll
            for (int rt = 0; rt < 2; ++rt)
#pragma unroll
                for (int j = 0; j < 4; ++j)
                    cqmin[(size_t)(wr0 + rt * 16 + lk * 4 + j) * NC16 + c16] = rmin[rt][j];
        }
#pragma unroll
        for (int rt = 0; rt < 2; ++rt)
#pragma unroll
            for (int j = 0; j < 4; ++j) {
                const float thr = fmaf(2.0f, epsv[rt][j], rmin[rt][j]);
                const int grow = wr0 + rt * 16 + lk * 4 + j;
#pragma unroll
                for (int ct = 0; ct < 4; ++ct) {
                    float dd = __fsub_rn(__fadd_rn(szv[rt][j], sse[c16 * 64 + ct * 16 + lr]),
                                         2.0f * acc[rt][ct][j]);
                    if (dd <= thr) {
                        int s = atomicAdd(&cnt[grow * NC8 + c8], 1);
                        if (s < SLOTS) {
                            size_t base = ((size_t)grow * NC8 + c8) * SLOTS + s;
                            cand_i[base] = c16 * 64 + ct * 16 + lr;
                            cand_d[base] = dd;
                        }
                    }
                }
            }
    }
}

// ---------------- rescore stage 1: global-window filter / fastpath ----------
// thr = gmin + 2eps. Candidates with stored d~ <= thr are the only possible
// argmins (d~_argmin <= d_argmin + eps <= gmin + 2eps). Exactly one -> done.
// Else (or overflow in a qualifying c8) -> worklist for the wave kernel.
__global__ __launch_bounds__(256) void rescore_fast_kernel(
    const float* __restrict__ epsr, const float* __restrict__ cqmin,
    const int* __restrict__ cnt, const float* __restrict__ cand_d,
    const int* __restrict__ cand_i, int* __restrict__ out_idx,
    float* __restrict__ out_idx_f, int* __restrict__ wl, int* __restrict__ wl_cnt) {
    const int row = blockIdx.x * 256 + threadIdx.x;
    float cq[NC16];
#pragma unroll
    for (int i = 0; i < 4; ++i)
        *(float4*)&cq[i * 4] = *(const float4*)(cqmin + (size_t)row * NC16 + i * 4);
    float gmin = __builtin_inff();
#pragma unroll
    for (int i = 0; i < NC16; ++i) gmin = fminf(gmin, cq[i]);
    const float thr = fmaf(2.0f, epsr[row], gmin);

    int nc = 0, uniq = 0;
    bool slow = false;
#pragma unroll
    for (int c8 = 0; c8 < NC8; ++c8) {
        if (fminf(cq[2 * c8], cq[2 * c8 + 1]) > thr) continue;
        int n = cnt[(size_t)row * NC8 + c8];
        if (n > SLOTS) { slow = true; }
        else {
            for (int s = 0; s < n; ++s) {
                size_t base = ((size_t)row * NC8 + c8) * SLOTS + s;
                if (cand_d[base] <= thr) { if (nc == 0) uniq = cand_i[base]; ++nc; }
            }
        }
    }
    if (!slow && nc == 1) {
        out_idx[row] = uniq;
        out_idx_f[row] = (float)uniq;
    } else {
        int p = atomicAdd(wl_cnt, 1);
        wl[p] = row;
    }
}

// ---------------- rescore stage 2: wave-per-row exact rescore ----------
// Lane l dots candidate l (exact sequential-k fmaf chain per candidate);
// 64-lane lexicographic (d, idx) reduce == np first-occurrence argmin.
__global__ __launch_bounds__(256) void rescore_slow_kernel(
    const float* __restrict__ z, const float* __restrict__ e,
    const float* __restrict__ sz, const float* __restrict__ se,
    const float* __restrict__ epsr, const float* __restrict__ cqmin,
    const int* __restrict__ cnt, const int* __restrict__ cand_i,
    const int* __restrict__ wl, const int* __restrict__ wl_cnt,
    int* __restrict__ out_idx, float* __restrict__ out_idx_f) {
    const int lane = threadIdx.x & 63;
    const int wave = (blockIdx.x * 256 + threadIdx.x) >> 6;
    const int nwaves = (gridDim.x * 256) >> 6;
    const int n_wl = wl_cnt[0];

    for (int i = wave; i < n_wl; i += nwaves) {
        const int row = wl[i];
        float gmin = __builtin_inff();
#pragma unroll
        for (int c16 = 0; c16 < NC16; ++c16)
            gmin = fminf(gmin, cqmin[(size_t)row * NC16 + c16]);
        const float thr = fmaf(2.0f, epsr[row], gmin);
        const float szr = sz[row];
        const float* zr = z + (size_t)row * ZDIM;
        float bd = __builtin_inff();
        int bi = 0x7fffffff;
#pragma unroll 1
        for (int c8 = 0; c8 < NC8; ++c8) {
            float cm = fminf(cqmin[(size_t)row * NC16 + 2 * c8],
                             cqmin[(size_t)row * NC16 + 2 * c8 + 1]);
            if (cm > thr) continue;
            int n = cnt[(size_t)row * NC8 + c8];
            if (n <= SLOTS) {
                if (lane < n) {
                    int c = cand_i[((size_t)row * NC8 + c8) * SLOTS + lane];
                    float m = exact_dot(zr, e + (size_t)c * ZDIM);
                    float d = __fsub_rn(__fadd_rn(szr, se[c]), 2.0f * m);
                    if (d < bd || (d == bd && c < bi)) { bd = d; bi = c; }
                }
            } else {
#pragma unroll
                for (int h = 0; h < 2; ++h) {
                    int c = c8 * 128 + h * 64 + lane;
                    float m = exact_dot(zr, e + (size_t)c * ZDIM);
                    float d = __fsub_rn(__fadd_rn(szr, se[c]), 2.0f * m);
                    if (d < bd || (d == bd && c < bi)) { bd = d; bi = c; }
                }
            }
        }
#pragma unroll
        for (int m = 1; m < 64; m <<= 1) {
            float od = __shfl_xor(bd, m, 64);
            int   oi = __shfl_xor(bi, m, 64);
            if (od < bd || (od == bd && oi < bi)) { bd = od; bi = oi; }
        }
        if (lane == 0) {
            out_idx[row] = bi;
            out_idx_f[row] = (float)bi;
        }
    }
}

// ---------------- z_q_st + loss partial (no atomics) ----------------
__global__ __launch_bounds__(256) void zq_loss_kernel(
    const float* __restrict__ z, const float* __restrict__ e,
    const int* __restrict__ idx, float* __restrict__ out,
    double* __restrict__ partial) {
    const int tid = threadIdx.x;
    const int rl  = tid >> 6;
    const int ln  = tid & 63;
    const int row0 = blockIdx.x * 32;

    float acc = 0.0f;
#pragma unroll
    for (int it = 0; it < 8; ++it) {
        int row = row0 + it * 4 + rl;
        int code = idx[row];
        const float4 vz = *(const float4*)(z + (size_t)row  * ZDIM + ln * 4);
        const float4 vq = *(const float4*)(e + (size_t)code * ZDIM + ln * 4);
        float4 o;
        float dx = __fsub_rn(vq.x, vz.x);
        float dy = __fsub_rn(vq.y, vz.y);
        float dz_ = __fsub_rn(vq.z, vz.z);
        float dw = __fsub_rn(vq.w, vz.w);
        o.x = __fadd_rn(vz.x, dx);
        o.y = __fadd_rn(vz.y, dy);
        o.z = __fadd_rn(vz.z, dz_);
        o.w = __fadd_rn(vz.w, dw);
        *(float4*)(out + (size_t)row * ZDIM + ln * 4) = o;
        acc = __fadd_rn(acc, __fmul_rn(dx, dx));
        acc = __fadd_rn(acc, __fmul_rn(dy, dy));
        acc = __fadd_rn(acc, __fmul_rn(dz_, dz_));
        acc = __fadd_rn(acc, __fmul_rn(dw, dw));
    }

    __shared__ double red[256];
    red[tid] = (double)acc;
    __syncthreads();
#pragma unroll
    for (int s = 128; s > 0; s >>= 1) {
        if (tid < s) red[tid] += red[tid + s];
        __syncthreads();
    }
    if (tid == 0) partial[blockIdx.x] = red[0];
}

__global__ __launch_bounds__(256) void loss_final_kernel(
    const double* __restrict__ partial, float* __restrict__ out_loss) {
    const int tid = threadIdx.x;
    double s = 0.0;
    for (int i = tid; i < ZQ_BLOCKS; i += 256) s += partial[i];
    __shared__ double red[256];
    red[tid] = s;
    __syncthreads();
#pragma unroll
    for (int st = 128; st > 0; st >>= 1) {
        if (tid < st) red[tid] += red[tid + st];
        __syncthreads();
    }
    if (tid == 0) {
        double M = red[0] / 16777216.0;
        float m32 = (float)M;
        out_loss[0] = __fadd_rn(m32, __fmul_rn(0.25f, m32));
    }
}

extern "C" void kernel_launch(void* const* d_in, const int* in_sizes, int n_in,
                              void* d_out, int out_size, void* d_ws, size_t ws_size,
                              hipStream_t stream) {
    const float* z = (const float*)d_in[0];
    const float* e = (const float*)d_in[1];
    float* out = (float*)d_out;
    char* ws = (char*)d_ws;

    size_t off = 0;
    double* partial = (double*)(ws + off); off += ZQ_BLOCKS * sizeof(double);        // 16 KB
    float*  sz      = (float*) (ws + off); off += (size_t)N_ROWS * 4;                // 256 KB
    float*  epsr    = (float*) (ws + off); off += (size_t)N_ROWS * 4;                // 256 KB
    float*  se      = (float*) (ws + off); off += (size_t)KCODES * 4;                // 4 KB
    int*    idx     = (int*)   (ws + off); off += (size_t)N_ROWS * 4;                // 256 KB
    u16*    ehf     = (u16*)   (ws + off); off += (size_t)KCODES * ZDIM * 2;         // 512 KB
    float*  cqmin   = (float*) (ws + off); off += (size_t)N_ROWS * NC16 * 4;         // 4 MB
    int*    cnt     = (int*)   (ws + off); off += (size_t)N_ROWS * NC8 * 4;          // 2 MB
    float*  cand_d  = (float*) (ws + off); off += (size_t)N_ROWS * NC8 * SLOTS * 4;  // 8 MB
    int*    cand_i  = (int*)   (ws + off); off += (size_t)N_ROWS * NC8 * SLOTS * 4;  // 8 MB
    int*    wl      = (int*)   (ws + off); off += (size_t)N_ROWS * 4;                // 256 KB
    int*    wl_cnt  = (int*)   (ws + off); off += 16;

    u16* zh = (u16*)out;   // bf16 z in d_out z_q region; zq_loss overwrites later

    hipMemsetAsync(cnt, 0, (size_t)N_ROWS * NC8 * 4, stream);
    hipMemsetAsync(wl_cnt, 0, 16, stream);
    split_z_kernel<<<8192, 256, 0, stream>>>(z, zh);
    split_e_kernel<<<256, 256, 0, stream>>>(e, ehf);
    rowsq_eps_kernel<<<N_ROWS / 256, 256, 0, stream>>>(z, sz, epsr);
    rowsq_kernel<<<KCODES / 256, 256, 0, stream>>>(e, se, KCODES);
    mfma_argmin_kernel<<<1024, 256, 0, stream>>>(zh, ehf, sz, se, epsr, cqmin, cnt, cand_d, cand_i);
    rescore_fast_kernel<<<N_ROWS / 256, 256, 0, stream>>>(epsr, cqmin, cnt, cand_d, cand_i,
                                                          idx, out + IDX_OFF, wl, wl_cnt);
    rescore_slow_kernel<<<1024, 256, 0, stream>>>(z, e, sz, se, epsr, cqmin, cnt, cand_i,
                                                  wl, wl_cnt, idx, out + IDX_OFF);
    zq_loss_kernel<<<ZQ_BLOCKS, 256, 0, stream>>>(z, e, idx, out, partial);
    loss_final_kernel<<<1, 256, 0, stream>>>(partial, out + LOSS_OFF);
}